// Round 26
// baseline (243.673 us; speedup 1.0000x reference)
//
#include <hip/hip_runtime.h>
#include <hip/hip_bf16.h>
#include <stdint.h>

// OPTIMIZED ROUND 9. Change vs R25: K-split 4 -> 8 (grid (16,8,8) = 1024
// blocks = 4/CU queued vs 3/CU LDS ceiling). R25's 4-panel loop was leaner
// per score (-36% LDS traffic) but its 512-block grid gave only 2 blocks/CU
// (occ 20%) — restore R22-level parallelism while keeping the lean loop.

typedef short bf16x8 __attribute__((ext_vector_type(8)));
typedef short short4v __attribute__((ext_vector_type(4)));
typedef float f32x4 __attribute__((ext_vector_type(4)));

#define LOG2E 1.4426950408889634f

__device__ __forceinline__ short f2bf(float f) {  // RNE
  union { float f; unsigned u; } x;
  x.f = f;
  unsigned r = (x.u + 0x7FFFu + ((x.u >> 16) & 1u)) >> 16;
  return (short)r;
}
__device__ __forceinline__ unsigned packbf2(float f0, float f1) {  // packed RNE cvt
  __hip_bfloat162 h = __float22bfloat162_rn(make_float2(f0, f1));
  unsigned u;
  __builtin_memcpy(&u, &h, 4);
  return u;
}

// ---------------- k0: fused prep (x cvt + Wc build)
__global__ __launch_bounds__(256) void prep(const float* __restrict__ xf,
                                            const float* __restrict__ W,
                                            const float* __restrict__ A,
                                            short* __restrict__ xb,
                                            short* __restrict__ Wc) {
  const int b = blockIdx.x;
  if (b < 1024) {
    const int i = (b * 256 + threadIdx.x) * 4;
    float4 v = *(const float4*)(xf + i);
    short4v s = {f2bf(v.x), f2bf(v.y), f2bf(v.z), f2bf(v.w)};
    *(short4v*)(xb + i) = s;
  } else {
    const int r = b - 1024;
    const int k = threadIdx.x;
    if (r < 512) {
      Wc[r * 256 + k] = f2bf(W[r * 256 + k]);
    } else {
      const int rr = r - 512;
      const int head = rr >> 6, e = rr & 63;
      float acc = 0.f;
      for (int dd = 0; dd < 64; ++dd) {
        acc += A[(head * 64 + dd) * 64 + e] * W[(head * 64 + dd) * 256 + k];
      }
      Wc[r * 256 + k] = f2bf(acc * LOG2E);  // exp2 domain
    }
  }
}

// ---------------- k1: hq = x @ Wc^T; h-col blocks (x<8) also emit hT tile.
__global__ __launch_bounds__(256) void gemm_hqT(const short* __restrict__ x,
                                                const short* __restrict__ Wc,
                                                short* __restrict__ hq,
                                                short* __restrict__ hT) {
  __shared__ short T[64 * 65];
  const int tid = threadIdx.x;
  const int wave = tid >> 6, lane = tid & 63;
  const int quad = lane >> 4, c = lane & 15;
  const int row0 = blockIdx.y * 64 + wave * 16;
  const int col0 = blockIdx.x * 64;

  f32x4 acc[4];
#pragma unroll
  for (int nt = 0; nt < 4; ++nt) acc[nt] = (f32x4){0.f, 0.f, 0.f, 0.f};
#pragma unroll
  for (int ks = 0; ks < 8; ++ks) {
    bf16x8 a = *(const bf16x8*)(x + (row0 + c) * 256 + ks * 32 + quad * 8);
#pragma unroll
    for (int nt = 0; nt < 4; ++nt) {
      bf16x8 b = *(const bf16x8*)(Wc + (col0 + nt * 16 + c) * 256 + ks * 32 + quad * 8);
      acc[nt] = __builtin_amdgcn_mfma_f32_16x16x32_bf16(a, b, acc[nt], 0, 0, 0);
    }
  }
#pragma unroll
  for (int nt = 0; nt < 4; ++nt)
#pragma unroll
    for (int r = 0; r < 4; ++r) {
      const short v = f2bf(acc[nt][r]);
      hq[(row0 + quad * 4 + r) * 1024 + col0 + nt * 16 + c] = v;
      T[(wave * 16 + quad * 4 + r) * 65 + nt * 16 + c] = v;
    }

  if (blockIdx.x < 8) {  // h columns: also write transposed hT[feat][node]
    __syncthreads();
    const int fl = tid >> 2, nch = (tid & 3) * 16;
    short vals[16];
#pragma unroll
    for (int i = 0; i < 16; ++i) vals[i] = T[(nch + i) * 65 + fl];
    bf16x8 lo = {vals[0], vals[1], vals[2], vals[3], vals[4], vals[5], vals[6], vals[7]};
    bf16x8 hi = {vals[8], vals[9], vals[10], vals[11], vals[12], vals[13], vals[14], vals[15]};
    short* dst = hT + (col0 + fl) * 4096 + blockIdx.y * 64 + nch;
    *(bf16x8*)dst = lo;
    *(bf16x8*)(dst + 8) = hi;
  }
}

// ---------------- k2: no-max flash, 64 queries/wave (4 panels), K-split x8.
// grid (16 qtiles(256q), 8 heads, 8 kslices); block 256 = 4 waves.
__global__ __launch_bounds__(256, 3) void attn_split(const short* __restrict__ hq,
                                                     const short* __restrict__ hT,
                                                     short* __restrict__ po,
                                                     float* __restrict__ pl) {
  const int tid = threadIdx.x;
  const int wave = tid >> 6, lane = tid & 63;
  const int quad = lane >> 4, c = lane & 15;
  const int head = blockIdx.y;
  const int q0 = blockIdx.x * 256 + wave * 64;

  __shared__ __align__(16) short K_lds[64 * 68];      // 8.7 KB
  __shared__ __align__(16) short Vt_lds[64 * 68];     // 8.7 KB
  __shared__ __align__(16) short P_lds[4 * 64 * 68];  // per-wave [q(64)][key(64)] 34.8 KB
  short* Pw = &P_lds[wave * 64 * 68];

  bf16x8 qf[4][2];
#pragma unroll
  for (int p = 0; p < 4; ++p) {
    const short* qb = hq + (q0 + p * 16 + c) * 1024 + 512 + head * 64 + quad * 8;
    qf[p][0] = *(const bf16x8*)qb;
    qf[p][1] = *(const bf16x8*)(qb + 32);
  }
  const short one = (short)0x3F80;
  const bf16x8 ones = {one, one, one, one, one, one, one, one};

  f32x4 o[4][4], ol[4];
#pragma unroll
  for (int p = 0; p < 4; ++p) {
#pragma unroll
    for (int mt = 0; mt < 4; ++mt) o[p][mt] = (f32x4){0.f, 0.f, 0.f, 0.f};
    ol[p] = (f32x4){0.f, 0.f, 0.f, 0.f};
  }

  // staging: 2 chunks/thread, pointers hoisted and incremented
  const int skey0 = tid >> 3, sdc = tid & 7;
  const int skey1 = (tid + 256) >> 3;
  const int kt0 = blockIdx.z * 8;
  const short* kp0 = hq + (size_t)(kt0 * 64 + skey0) * 1024 + head * 64 + sdc * 8;
  const short* kp1 = hq + (size_t)(kt0 * 64 + skey1) * 1024 + head * 64 + sdc * 8;
  const short* vp0 = hT + (size_t)(head * 64 + skey0) * 4096 + kt0 * 64 + sdc * 8;
  const short* vp1 = hT + (size_t)(head * 64 + skey1) * 4096 + kt0 * 64 + sdc * 8;

  for (int it = 0; it < 8; ++it) {
    __syncthreads();
    {
      bf16x8 v0 = *(const bf16x8*)kp0;
      bf16x8 v1 = *(const bf16x8*)kp1;
      *(bf16x8*)&K_lds[skey0 * 68 + sdc * 8] = v0;
      *(bf16x8*)&K_lds[skey1 * 68 + sdc * 8] = v1;
      bf16x8 w0 = *(const bf16x8*)vp0;
      bf16x8 w1 = *(const bf16x8*)vp1;
      *(bf16x8*)&Vt_lds[skey0 * 68 + sdc * 8] = w0;
      *(bf16x8*)&Vt_lds[skey1 * 68 + sdc * 8] = w1;
      kp0 += 64 * 1024; kp1 += 64 * 1024;
      vp0 += 64;        vp1 += 64;
    }
    __syncthreads();

    // scores: K frags shared across 4 Q panels
#pragma unroll
    for (int mt = 0; mt < 4; ++mt) {
      bf16x8 a0 = *(const bf16x8*)&K_lds[(mt * 16 + c) * 68 + quad * 8];
      bf16x8 a1 = *(const bf16x8*)&K_lds[(mt * 16 + c) * 68 + 32 + quad * 8];
#pragma unroll
      for (int p = 0; p < 4; ++p) {
        f32x4 s = (f32x4){0.f, 0.f, 0.f, 0.f};
        s = __builtin_amdgcn_mfma_f32_16x16x32_bf16(a0, qf[p][0], s, 0, 0, 0);
        s = __builtin_amdgcn_mfma_f32_16x16x32_bf16(a1, qf[p][1], s, 0, 0, 0);
        const float p0 = exp2f(fmaxf(s[0], 0.2f * s[0]));
        const float p1 = exp2f(fmaxf(s[1], 0.2f * s[1]));
        const float p2 = exp2f(fmaxf(s[2], 0.2f * s[2]));
        const float p3 = exp2f(fmaxf(s[3], 0.2f * s[3]));
        uint2 d = {packbf2(p0, p1), packbf2(p2, p3)};
        *(uint2*)&Pw[(p * 16 + c) * 68 + mt * 16 + quad * 4] = d;
      }
    }
    // P reads + PV + l, panel by panel (wave-private LDS; lgkmcnt-ordered)
#pragma unroll
    for (int p = 0; p < 4; ++p) {
      short4v r0 = *(const short4v*)&Pw[(p * 16 + c) * 68 + quad * 8];
      short4v r1 = *(const short4v*)&Pw[(p * 16 + c) * 68 + quad * 8 + 4];
      short4v r2 = *(const short4v*)&Pw[(p * 16 + c) * 68 + 32 + quad * 8];
      short4v r3 = *(const short4v*)&Pw[(p * 16 + c) * 68 + 32 + quad * 8 + 4];
      bf16x8 pb0 = {r0[0], r0[1], r0[2], r0[3], r1[0], r1[1], r1[2], r1[3]};
      bf16x8 pb1 = {r2[0], r2[1], r2[2], r2[3], r3[0], r3[1], r3[2], r3[3]};
#pragma unroll
      for (int mt = 0; mt < 4; ++mt) {
        bf16x8 va0 = *(const bf16x8*)&Vt_lds[(mt * 16 + c) * 68 + quad * 8];
        bf16x8 va1 = *(const bf16x8*)&Vt_lds[(mt * 16 + c) * 68 + 32 + quad * 8];
        o[p][mt] = __builtin_amdgcn_mfma_f32_16x16x32_bf16(va0, pb0, o[p][mt], 0, 0, 0);
        o[p][mt] = __builtin_amdgcn_mfma_f32_16x16x32_bf16(va1, pb1, o[p][mt], 0, 0, 0);
      }
      ol[p] = __builtin_amdgcn_mfma_f32_16x16x32_bf16(ones, pb0, ol[p], 0, 0, 0);
      ol[p] = __builtin_amdgcn_mfma_f32_16x16x32_bf16(ones, pb1, ol[p], 0, 0, 0);
    }
  }

  // epilogue: bf16 partials [256 q][64 d] + l per panel
  const int pbi = (blockIdx.x * 8 + blockIdx.y) * 8 + blockIdx.z;
  short* po_b = po + (size_t)pbi * 16384;
#pragma unroll
  for (int p = 0; p < 4; ++p) {
    const int ql = wave * 64 + p * 16 + c;
#pragma unroll
    for (int mt = 0; mt < 4; ++mt) {
      short4v o4 = {f2bf(o[p][mt][0]), f2bf(o[p][mt][1]),
                    f2bf(o[p][mt][2]), f2bf(o[p][mt][3])};
      *(short4v*)&po_b[ql * 64 + mt * 16 + quad * 4] = o4;
    }
    if (quad == 0) pl[pbi * 256 + ql] = ol[p][0];
  }
}

// ---------------- k3: merge 8 kslices (bf16 partials -> f32 out)
__global__ __launch_bounds__(256) void merge8(const short* __restrict__ po,
                                              const float* __restrict__ pl,
                                              float* __restrict__ out) {
  const int qt = blockIdx.x, head = blockIdx.y, t = threadIdx.x;  // qt: 64-q group
  const int q = t >> 2, dg = t & 3;
  const int q256 = (qt & 3) * 64 + q;
  const int pbb = ((qt >> 2) * 8 + head) * 8;
  float lsum = 0.f;
#pragma unroll
  for (int z = 0; z < 8; ++z) lsum += pl[(pbb + z) * 256 + q256];
  const float inv = 1.0f / lsum;
  float a[16];
#pragma unroll
  for (int i = 0; i < 16; ++i) a[i] = 0.f;
#pragma unroll
  for (int z = 0; z < 8; ++z) {
    const short* p = po + (size_t)(pbb + z) * 16384 + q256 * 64 + dg * 16;
    bf16x8 lo = *(const bf16x8*)p;
    bf16x8 hi = *(const bf16x8*)(p + 8);
#pragma unroll
    for (int i = 0; i < 8; ++i) {
      union { unsigned u; float f; } x, y;
      x.u = ((unsigned)(unsigned short)lo[i]) << 16;
      y.u = ((unsigned)(unsigned short)hi[i]) << 16;
      a[i] += x.f;
      a[i + 8] += y.f;
    }
  }
  float* op = out + (qt * 64 + q) * 512 + head * 64 + dg * 16;
#pragma unroll
  for (int i = 0; i < 4; ++i) {
    float4 r = {a[i * 4] * inv, a[i * 4 + 1] * inv, a[i * 4 + 2] * inv, a[i * 4 + 3] * inv};
    *(float4*)(op + i * 4) = r;
  }
}

extern "C" void kernel_launch(void* const* d_in, const int* in_sizes, int n_in,
                              void* d_out, int out_size, void* d_ws, size_t ws_size,
                              hipStream_t stream) {
  const float* x = (const float*)d_in[0];
  const float* W = (const float*)d_in[2];
  const float* A = (const float*)d_in[3];
  for (int i = 0; i < n_in; ++i) {
    if (in_sizes[i] == 4096 * 256) x = (const float*)d_in[i];
    else if (in_sizes[i] == 512 * 256) W = (const float*)d_in[i];
    else if (in_sizes[i] == 8 * 64 * 64) A = (const float*)d_in[i];
  }

  float* out = (float*)d_out;                 // [4096][512] f32
  short* xb = (short*)d_ws;                   // 2 MB
  short* Wc = xb + 4096 * 256;                // 0.5 MB
  short* hq = Wc + 1024 * 256;                // 8 MB
  short* hT = hq + 4096 * 1024;               // 4 MB
  short* po = hT + 512 * 4096;                // 1024*16384*2 = 33.6 MB
  float* pl = (float*)(po + (size_t)1024 * 16384);  // 1 MB

  prep<<<dim3(2048), dim3(256), 0, stream>>>(x, W, A, xb, Wc);
  gemm_hqT<<<dim3(16, 64), dim3(256), 0, stream>>>(xb, Wc, hq, hT);
  attn_split<<<dim3(16, 8, 8), dim3(256), 0, stream>>>(hq, hT, po, pl);
  merge8<<<dim3(64, 8), dim3(256), 0, stream>>>(po, pl, out);
}

// Round 27
// 197.952 us; speedup vs baseline: 1.2310x; 1.2310x over previous
//
#include <hip/hip_runtime.h>
#include <stdint.h>

// REVERT TO SESSION BEST (R22): 2 Q-panels/wave, K-split x4, grid (32,8,4),
// stride-68 conflict-free LDS, ones-MFMA l, bf16 po partials, fused hT,
// no-max exp2, manual pair pack. Measured 198.8 us total / 82 us attn.
// R23-R26 excursions (8-wave blocks, VGPR caps, 4-panel, K-split 8) all
// regressed or were neutral — this configuration is the plateau attractor.

typedef short bf16x8 __attribute__((ext_vector_type(8)));
typedef short short4v __attribute__((ext_vector_type(4)));
typedef float f32x4 __attribute__((ext_vector_type(4)));

#define LOG2E 1.4426950408889634f

__device__ __forceinline__ short f2bf(float f) {  // RNE
  union { float f; unsigned u; } x;
  x.f = f;
  unsigned r = (x.u + 0x7FFFu + ((x.u >> 16) & 1u)) >> 16;
  return (short)r;
}
__device__ __forceinline__ unsigned pack2(float f0, float f1) {  // half-up pair
  union { float f; unsigned u; } a, b;
  a.f = f0; b.f = f1;
  return ((a.u + 0x8000u) >> 16) | ((b.u + 0x8000u) & 0xFFFF0000u);
}

// ---------------- k0: fused prep (x cvt + Wc build)
__global__ __launch_bounds__(256) void prep(const float* __restrict__ xf,
                                            const float* __restrict__ W,
                                            const float* __restrict__ A,
                                            short* __restrict__ xb,
                                            short* __restrict__ Wc) {
  const int b = blockIdx.x;
  if (b < 1024) {
    const int i = (b * 256 + threadIdx.x) * 4;
    float4 v = *(const float4*)(xf + i);
    short4v s = {f2bf(v.x), f2bf(v.y), f2bf(v.z), f2bf(v.w)};
    *(short4v*)(xb + i) = s;
  } else {
    const int r = b - 1024;
    const int k = threadIdx.x;
    if (r < 512) {
      Wc[r * 256 + k] = f2bf(W[r * 256 + k]);
    } else {
      const int rr = r - 512;
      const int head = rr >> 6, e = rr & 63;
      float acc = 0.f;
      for (int dd = 0; dd < 64; ++dd) {
        acc += A[(head * 64 + dd) * 64 + e] * W[(head * 64 + dd) * 256 + k];
      }
      Wc[r * 256 + k] = f2bf(acc * LOG2E);  // exp2 domain
    }
  }
}

// ---------------- k1: hq = x @ Wc^T; h-col blocks (x<8) also emit hT tile.
__global__ __launch_bounds__(256) void gemm_hqT(const short* __restrict__ x,
                                                const short* __restrict__ Wc,
                                                short* __restrict__ hq,
                                                short* __restrict__ hT) {
  __shared__ short T[64 * 65];
  const int tid = threadIdx.x;
  const int wave = tid >> 6, lane = tid & 63;
  const int quad = lane >> 4, c = lane & 15;
  const int row0 = blockIdx.y * 64 + wave * 16;
  const int col0 = blockIdx.x * 64;

  f32x4 acc[4];
#pragma unroll
  for (int nt = 0; nt < 4; ++nt) acc[nt] = (f32x4){0.f, 0.f, 0.f, 0.f};
#pragma unroll
  for (int ks = 0; ks < 8; ++ks) {
    bf16x8 a = *(const bf16x8*)(x + (row0 + c) * 256 + ks * 32 + quad * 8);
#pragma unroll
    for (int nt = 0; nt < 4; ++nt) {
      bf16x8 b = *(const bf16x8*)(Wc + (col0 + nt * 16 + c) * 256 + ks * 32 + quad * 8);
      acc[nt] = __builtin_amdgcn_mfma_f32_16x16x32_bf16(a, b, acc[nt], 0, 0, 0);
    }
  }
#pragma unroll
  for (int nt = 0; nt < 4; ++nt)
#pragma unroll
    for (int r = 0; r < 4; ++r) {
      const short v = f2bf(acc[nt][r]);
      hq[(row0 + quad * 4 + r) * 1024 + col0 + nt * 16 + c] = v;
      T[(wave * 16 + quad * 4 + r) * 65 + nt * 16 + c] = v;
    }

  if (blockIdx.x < 8) {  // h columns: also write transposed hT[feat][node]
    __syncthreads();
    const int fl = tid >> 2, nch = (tid & 3) * 16;
    short vals[16];
#pragma unroll
    for (int i = 0; i < 16; ++i) vals[i] = T[(nch + i) * 65 + fl];
    bf16x8 lo = {vals[0], vals[1], vals[2], vals[3], vals[4], vals[5], vals[6], vals[7]};
    bf16x8 hi = {vals[8], vals[9], vals[10], vals[11], vals[12], vals[13], vals[14], vals[15]};
    short* dst = hT + (col0 + fl) * 4096 + blockIdx.y * 64 + nch;
    *(bf16x8*)dst = lo;
    *(bf16x8*)(dst + 8) = hi;
  }
}

// ---------------- k2: no-max flash, 32 queries/wave, K-split x4.
// grid (32 qtiles(128q), 8 heads, 4 kslices); block 256 = 4 waves.
__global__ __launch_bounds__(256, 4) void attn_split(const short* __restrict__ hq,
                                                     const short* __restrict__ hT,
                                                     short* __restrict__ po,
                                                     float* __restrict__ pl) {
  const int tid = threadIdx.x;
  const int wave = tid >> 6, lane = tid & 63;
  const int quad = lane >> 4, c = lane & 15;
  const int head = blockIdx.y;
  const int q0 = blockIdx.x * 128 + wave * 32;

  __shared__ __align__(16) short K_lds[64 * 68];      // [key][dim]
  __shared__ __align__(16) short Vt_lds[64 * 68];     // [dim][key]
  __shared__ __align__(16) short P_lds[4 * 32 * 68];  // per-wave [q(32)][key(64)]
  short* Pw = &P_lds[wave * 32 * 68];

  bf16x8 qf[2][2];
#pragma unroll
  for (int p = 0; p < 2; ++p) {
    const short* qb = hq + (q0 + p * 16 + c) * 1024 + 512 + head * 64 + quad * 8;
    qf[p][0] = *(const bf16x8*)qb;
    qf[p][1] = *(const bf16x8*)(qb + 32);
  }
  const short one = (short)0x3F80;
  const bf16x8 ones = {one, one, one, one, one, one, one, one};

  f32x4 o[2][4], ol[2];
#pragma unroll
  for (int p = 0; p < 2; ++p) {
#pragma unroll
    for (int mt = 0; mt < 4; ++mt) o[p][mt] = (f32x4){0.f, 0.f, 0.f, 0.f};
    ol[p] = (f32x4){0.f, 0.f, 0.f, 0.f};
  }

  const int kt0 = blockIdx.z * 16;
  for (int kt = kt0; kt < kt0 + 16; ++kt) {
    __syncthreads();
#pragma unroll
    for (int pp = 0; pp < 2; ++pp) {
      const int chunk = tid + pp * 256;
      const int key = chunk >> 3, dc = chunk & 7;
      bf16x8 v = *(const bf16x8*)(hq + (kt * 64 + key) * 1024 + head * 64 + dc * 8);
      *(bf16x8*)&K_lds[key * 68 + dc * 8] = v;
      bf16x8 w = *(const bf16x8*)(hT + (head * 64 + key) * 4096 + kt * 64 + dc * 8);
      *(bf16x8*)&Vt_lds[key * 68 + dc * 8] = w;
    }
    __syncthreads();

    // scores: K frags shared across both Q panels
#pragma unroll
    for (int mt = 0; mt < 4; ++mt) {
      bf16x8 a0 = *(const bf16x8*)&K_lds[(mt * 16 + c) * 68 + quad * 8];
      bf16x8 a1 = *(const bf16x8*)&K_lds[(mt * 16 + c) * 68 + 32 + quad * 8];
#pragma unroll
      for (int p = 0; p < 2; ++p) {
        f32x4 s = (f32x4){0.f, 0.f, 0.f, 0.f};
        s = __builtin_amdgcn_mfma_f32_16x16x32_bf16(a0, qf[p][0], s, 0, 0, 0);
        s = __builtin_amdgcn_mfma_f32_16x16x32_bf16(a1, qf[p][1], s, 0, 0, 0);
        const float p0 = exp2f(fmaxf(s[0], 0.2f * s[0]));
        const float p1 = exp2f(fmaxf(s[1], 0.2f * s[1]));
        const float p2 = exp2f(fmaxf(s[2], 0.2f * s[2]));
        const float p3 = exp2f(fmaxf(s[3], 0.2f * s[3]));
        uint2 d = {pack2(p0, p1), pack2(p2, p3)};
        *(uint2*)&Pw[(p * 16 + c) * 68 + mt * 16 + quad * 4] = d;
      }
    }
    // P reads (wave-private LDS; compiler orders via lgkmcnt)
    bf16x8 pb[2][2];
#pragma unroll
    for (int p = 0; p < 2; ++p) {
      short4v r0 = *(const short4v*)&Pw[(p * 16 + c) * 68 + quad * 8];
      short4v r1 = *(const short4v*)&Pw[(p * 16 + c) * 68 + quad * 8 + 4];
      short4v r2 = *(const short4v*)&Pw[(p * 16 + c) * 68 + 32 + quad * 8];
      short4v r3 = *(const short4v*)&Pw[(p * 16 + c) * 68 + 32 + quad * 8 + 4];
      pb[p][0] = (bf16x8){r0[0], r0[1], r0[2], r0[3], r1[0], r1[1], r1[2], r1[3]};
      pb[p][1] = (bf16x8){r2[0], r2[1], r2[2], r2[3], r3[0], r3[1], r3[2], r3[3]};
    }
    // PV: Vt frags shared across both panels
#pragma unroll
    for (int mt = 0; mt < 4; ++mt) {
      bf16x8 va0 = *(const bf16x8*)&Vt_lds[(mt * 16 + c) * 68 + quad * 8];
      bf16x8 va1 = *(const bf16x8*)&Vt_lds[(mt * 16 + c) * 68 + 32 + quad * 8];
#pragma unroll
      for (int p = 0; p < 2; ++p) {
        o[p][mt] = __builtin_amdgcn_mfma_f32_16x16x32_bf16(va0, pb[p][0], o[p][mt], 0, 0, 0);
        o[p][mt] = __builtin_amdgcn_mfma_f32_16x16x32_bf16(va1, pb[p][1], o[p][mt], 0, 0, 0);
      }
    }
#pragma unroll
    for (int p = 0; p < 2; ++p) {
      ol[p] = __builtin_amdgcn_mfma_f32_16x16x32_bf16(ones, pb[p][0], ol[p], 0, 0, 0);
      ol[p] = __builtin_amdgcn_mfma_f32_16x16x32_bf16(ones, pb[p][1], ol[p], 0, 0, 0);
    }
  }

  // epilogue: bf16 partials + l per panel
  const int pbi = (blockIdx.x * 8 + blockIdx.y) * 4 + blockIdx.z;
  short* po_b = po + (size_t)pbi * 8192;  // [128 q][64 d]
#pragma unroll
  for (int p = 0; p < 2; ++p) {
    const int ql = wave * 32 + p * 16 + c;
#pragma unroll
    for (int mt = 0; mt < 4; ++mt) {
      short4v o4 = {f2bf(o[p][mt][0]), f2bf(o[p][mt][1]),
                    f2bf(o[p][mt][2]), f2bf(o[p][mt][3])};
      *(short4v*)&po_b[ql * 64 + mt * 16 + quad * 4] = o4;
    }
    if (quad == 0) pl[pbi * 128 + ql] = ol[p][0];
  }
}

// ---------------- k3: merge 4 kslices (bf16 partials -> f32 out)
__global__ __launch_bounds__(256) void merge4(const short* __restrict__ po,
                                              const float* __restrict__ pl,
                                              float* __restrict__ out) {
  const int qt = blockIdx.x, head = blockIdx.y, t = threadIdx.x;  // qt: 64-q group
  const int q = t >> 2, dg = t & 3;
  const int q128 = (qt & 1) * 64 + q;
  const int pbb = ((qt >> 1) * 8 + head) * 4;
  const float inv = 1.0f / (pl[pbb * 128 + q128] + pl[(pbb + 1) * 128 + q128] +
                            pl[(pbb + 2) * 128 + q128] + pl[(pbb + 3) * 128 + q128]);
  float a[16];
#pragma unroll
  for (int i = 0; i < 16; ++i) a[i] = 0.f;
#pragma unroll
  for (int z = 0; z < 4; ++z) {
    const short* p = po + (size_t)(pbb + z) * 8192 + q128 * 64 + dg * 16;
    bf16x8 lo = *(const bf16x8*)p;
    bf16x8 hi = *(const bf16x8*)(p + 8);
#pragma unroll
    for (int i = 0; i < 8; ++i) {
      union { unsigned u; float f; } x, y;
      x.u = ((unsigned)(unsigned short)lo[i]) << 16;
      y.u = ((unsigned)(unsigned short)hi[i]) << 16;
      a[i] += x.f;
      a[i + 8] += y.f;
    }
  }
  float* op = out + (qt * 64 + q) * 512 + head * 64 + dg * 16;
#pragma unroll
  for (int i = 0; i < 4; ++i) {
    float4 r = {a[i * 4] * inv, a[i * 4 + 1] * inv, a[i * 4 + 2] * inv, a[i * 4 + 3] * inv};
    *(float4*)(op + i * 4) = r;
  }
}

extern "C" void kernel_launch(void* const* d_in, const int* in_sizes, int n_in,
                              void* d_out, int out_size, void* d_ws, size_t ws_size,
                              hipStream_t stream) {
  const float* x = (const float*)d_in[0];
  const float* W = (const float*)d_in[2];
  const float* A = (const float*)d_in[3];
  for (int i = 0; i < n_in; ++i) {
    if (in_sizes[i] == 4096 * 256) x = (const float*)d_in[i];
    else if (in_sizes[i] == 512 * 256) W = (const float*)d_in[i];
    else if (in_sizes[i] == 8 * 64 * 64) A = (const float*)d_in[i];
  }

  float* out = (float*)d_out;                 // [4096][512] f32
  short* xb = (short*)d_ws;                   // 2 MB
  short* Wc = xb + 4096 * 256;                // 0.5 MB
  short* hq = Wc + 1024 * 256;                // 8 MB
  short* hT = hq + 4096 * 1024;               // 4 MB
  short* po = hT + 512 * 4096;                // 1024*8192*2 = 16.8 MB
  float* pl = (float*)(po + (size_t)1024 * 8192);  // 0.5 MB

  prep<<<dim3(2048), dim3(256), 0, stream>>>(x, W, A, xb, Wc);
  gemm_hqT<<<dim3(16, 64), dim3(256), 0, stream>>>(xb, Wc, hq, hT);
  attn_split<<<dim3(32, 8, 4), dim3(256), 0, stream>>>(hq, hT, po, pl);
  merge4<<<dim3(64, 8), dim3(256), 0, stream>>>(po, pl, out);
}